// Round 1
// baseline (1437.306 us; speedup 1.0000x reference)
//
#include <hip/hip_runtime.h>
#include <hip/hip_bf16.h>

// Problem constants (match reference)
#define NN 100000      // N_GRAPHS * NUM_GENES
#define EE 1600000     // edges
#define HD 64          // hidden = F_IN = EMB = 64
#define SLOPE 0.01f
#define BN_EPS 1e-5f

__device__ __forceinline__ float bcast(float v, int i) {
    return __uint_as_float((unsigned)__builtin_amdgcn_readlane((int)__float_as_uint(v), i));
}

__device__ __forceinline__ float lrelu(float v) {
    return v > 0.f ? v : SLOPE * v;
}

// h = x @ W + b   (one GEMV per row; 4 rows per wave, lane = output feature)
__global__ __launch_bounds__(256) void k_pre(const float* __restrict__ x,
                                             const float* __restrict__ W,
                                             const float* __restrict__ b,
                                             float* __restrict__ h) {
    __shared__ float Ws[HD * HD];
    int tid = threadIdx.x;
    for (int k = tid; k < HD * HD / 4; k += 256) {
        ((float4*)Ws)[k] = ((const float4*)W)[k];
    }
    __syncthreads();
    int lane = tid & 63;
    int gw = (blockIdx.x * 256 + tid) >> 6;
    int nw = (gridDim.x * 256) >> 6;
    float bb = b[lane];
    for (int row0 = gw * 4; row0 < NN; row0 += nw * 4) {
        float z[4], y[4];
#pragma unroll
        for (int r = 0; r < 4; r++) {
            z[r] = x[(size_t)(row0 + r) * HD + lane];
            y[r] = bb;
        }
        for (int i = 0; i < HD; i++) {
            float w = Ws[i * HD + lane];
#pragma unroll
            for (int r = 0; r < 4; r++) y[r] = fmaf(bcast(z[r], i), w, y[r]);
        }
#pragma unroll
        for (int r = 0; r < 4; r++) h[(size_t)(row0 + r) * HD + lane] = y[r];
    }
}

// agg[dst] += h[src] over all edges; wave per edge, 8 edges unrolled
__global__ __launch_bounds__(256) void k_scatter(const int* __restrict__ src,
                                                 const int* __restrict__ dst,
                                                 const float* __restrict__ h,
                                                 float* __restrict__ agg) {
    int lane = threadIdx.x & 63;
    int gw = (blockIdx.x * 256 + threadIdx.x) >> 6;
    int nw = (gridDim.x * 256) >> 6;
    for (int base = gw * 8; base < EE; base += nw * 8) {
        int s[8], d[8];
#pragma unroll
        for (int k = 0; k < 8; k++) {
            s[k] = src[base + k];
            d[k] = dst[base + k];
        }
        float v[8];
#pragma unroll
        for (int k = 0; k < 8; k++) v[k] = h[(size_t)s[k] * HD + lane];
#pragma unroll
        for (int k = 0; k < 8; k++) atomicAdd(&agg[(size_t)d[k] * HD + lane], v[k]);
    }
}

// z = h + agg; t = lrelu(z@w1+b1); o = t@w2+b2 -> hout (in place over h ok);
// accumulates BN partial sums into stats[0:64]=sum, stats[64:128]=sumsq
__global__ __launch_bounds__(256) void k_conv(const float* __restrict__ h,
                                              const float* __restrict__ agg,
                                              const float* __restrict__ w1,
                                              const float* __restrict__ b1,
                                              const float* __restrict__ w2,
                                              const float* __restrict__ b2,
                                              float* __restrict__ hout,
                                              float* __restrict__ stats) {
    __shared__ float w1s[HD * HD];
    __shared__ float w2s[HD * HD];
    int tid = threadIdx.x;
    for (int k = tid; k < HD * HD / 4; k += 256) {
        ((float4*)w1s)[k] = ((const float4*)w1)[k];
        ((float4*)w2s)[k] = ((const float4*)w2)[k];
    }
    __syncthreads();
    int lane = tid & 63;
    int gw = (blockIdx.x * 256 + tid) >> 6;
    int nw = (gridDim.x * 256) >> 6;
    float bb1 = b1[lane], bb2 = b2[lane];
    float s1 = 0.f, s2 = 0.f;
    for (int row0 = gw * 4; row0 < NN; row0 += nw * 4) {
        float z[4], y[4];
#pragma unroll
        for (int r = 0; r < 4; r++) {
            size_t o = (size_t)(row0 + r) * HD + lane;
            z[r] = h[o] + agg[o];
            y[r] = bb1;
        }
        for (int i = 0; i < HD; i++) {
            float w = w1s[i * HD + lane];
#pragma unroll
            for (int r = 0; r < 4; r++) y[r] = fmaf(bcast(z[r], i), w, y[r]);
        }
#pragma unroll
        for (int r = 0; r < 4; r++) {
            z[r] = lrelu(y[r]);
            y[r] = bb2;
        }
        for (int i = 0; i < HD; i++) {
            float w = w2s[i * HD + lane];
#pragma unroll
            for (int r = 0; r < 4; r++) y[r] = fmaf(bcast(z[r], i), w, y[r]);
        }
#pragma unroll
        for (int r = 0; r < 4; r++) {
            size_t o = (size_t)(row0 + r) * HD + lane;
            hout[o] = y[r];
            s1 += y[r];
            s2 += y[r] * y[r];
        }
    }
    atomicAdd(&stats[lane], s1);
    atomicAdd(&stats[64 + lane], s2);
}

// batchnorm in place using stats
__global__ __launch_bounds__(256) void k_bn(float* __restrict__ h,
                                            const float* __restrict__ stats,
                                            const float* __restrict__ g,
                                            const float* __restrict__ b) {
    int idx = blockIdx.x * 256 + threadIdx.x;
    int j = idx & 63;
    float inv = 1.f / (float)NN;
    float mu = stats[j] * inv;
    float var = stats[64 + j] * inv - mu * mu;
    float sc = rsqrtf(var + BN_EPS) * g[j];
    float sh = b[j] - mu * sc;
    size_t total = (size_t)NN * HD;
    size_t stride = (size_t)gridDim.x * 256;
    for (size_t i = idx; i < total; i += stride) h[i] = h[i] * sc + sh;
}

// final: conv3 mlp + post mlp -> out (f32)
__global__ __launch_bounds__(256) void k_final(const float* __restrict__ h,
                                               const float* __restrict__ agg,
                                               const float* __restrict__ w1,
                                               const float* __restrict__ b1,
                                               const float* __restrict__ w2,
                                               const float* __restrict__ b2,
                                               const float* __restrict__ pw1,
                                               const float* __restrict__ pb1,
                                               const float* __restrict__ pw2,
                                               const float* __restrict__ pb2,
                                               float* __restrict__ out) {
    __shared__ float w1s[HD * HD];
    __shared__ float w2s[HD * HD];
    __shared__ float pw1s[HD * HD];
    __shared__ float pw2s[HD * HD];
    int tid = threadIdx.x;
    for (int k = tid; k < HD * HD / 4; k += 256) {
        ((float4*)w1s)[k] = ((const float4*)w1)[k];
        ((float4*)w2s)[k] = ((const float4*)w2)[k];
        ((float4*)pw1s)[k] = ((const float4*)pw1)[k];
        ((float4*)pw2s)[k] = ((const float4*)pw2)[k];
    }
    __syncthreads();
    int lane = tid & 63;
    int gw = (blockIdx.x * 256 + tid) >> 6;
    int nw = (gridDim.x * 256) >> 6;
    float bb1 = b1[lane], bb2 = b2[lane], pbb1 = pb1[lane], pbb2 = pb2[lane];
    for (int row0 = gw * 4; row0 < NN; row0 += nw * 4) {
        float z[4], y[4];
#pragma unroll
        for (int r = 0; r < 4; r++) {
            size_t o = (size_t)(row0 + r) * HD + lane;
            z[r] = h[o] + agg[o];
            y[r] = bb1;
        }
        for (int i = 0; i < HD; i++) {
            float w = w1s[i * HD + lane];
#pragma unroll
            for (int r = 0; r < 4; r++) y[r] = fmaf(bcast(z[r], i), w, y[r]);
        }
#pragma unroll
        for (int r = 0; r < 4; r++) { z[r] = lrelu(y[r]); y[r] = bb2; }
        for (int i = 0; i < HD; i++) {
            float w = w2s[i * HD + lane];
#pragma unroll
            for (int r = 0; r < 4; r++) y[r] = fmaf(bcast(z[r], i), w, y[r]);
        }
        // post mlp
#pragma unroll
        for (int r = 0; r < 4; r++) { z[r] = y[r]; y[r] = pbb1; }
        for (int i = 0; i < HD; i++) {
            float w = pw1s[i * HD + lane];
#pragma unroll
            for (int r = 0; r < 4; r++) y[r] = fmaf(bcast(z[r], i), w, y[r]);
        }
#pragma unroll
        for (int r = 0; r < 4; r++) { z[r] = lrelu(y[r]); y[r] = pbb2; }
        for (int i = 0; i < HD; i++) {
            float w = pw2s[i * HD + lane];
#pragma unroll
            for (int r = 0; r < 4; r++) y[r] = fmaf(bcast(z[r], i), w, y[r]);
        }
#pragma unroll
        for (int r = 0; r < 4; r++) out[(size_t)(row0 + r) * HD + lane] = y[r];
    }
}

extern "C" void kernel_launch(void* const* d_in, const int* in_sizes, int n_in,
                              void* d_out, int out_size, void* d_ws, size_t ws_size,
                              hipStream_t stream) {
    const float* x = (const float*)d_in[0];
    const int* edge = (const int*)d_in[1];
    const float* pre_w = (const float*)d_in[2];
    const float* pre_b = (const float*)d_in[3];
    const float* conv_w1 = (const float*)d_in[4];
    const float* conv_b1 = (const float*)d_in[5];
    const float* conv_w2 = (const float*)d_in[6];
    const float* conv_b2 = (const float*)d_in[7];
    const float* bn_g = (const float*)d_in[8];
    const float* bn_b = (const float*)d_in[9];
    const float* post_w1 = (const float*)d_in[10];
    const float* post_b1 = (const float*)d_in[11];
    const float* post_w2 = (const float*)d_in[12];
    const float* post_b2 = (const float*)d_in[13];
    float* out = (float*)d_out;

    const int* src = edge;        // edge_index[0]
    const int* dst = edge + EE;   // edge_index[1]

    float* hA = (float*)d_ws;                         // N*64 f32
    float* hB = hA + (size_t)NN * HD;                 // N*64 f32 (agg)
    float* stats = hB + (size_t)NN * HD;              // 128 f32

    const size_t hbytes = (size_t)NN * HD * sizeof(float);

    dim3 blk(256);
    dim3 gConv(1024), gScat(4096), gBn(1024);

    // pre-linear
    hipLaunchKernelGGL(k_pre, gConv, blk, 0, stream, x, pre_w, pre_b, hA);

    for (int l = 0; l < 2; l++) {
        hipMemsetAsync(hB, 0, hbytes, stream);
        hipLaunchKernelGGL(k_scatter, gScat, blk, 0, stream, src, dst, hA, hB);
        hipMemsetAsync(stats, 0, 128 * sizeof(float), stream);
        hipLaunchKernelGGL(k_conv, gConv, blk, 0, stream, hA, hB,
                           conv_w1 + (size_t)l * HD * HD, conv_b1 + (size_t)l * HD,
                           conv_w2 + (size_t)l * HD * HD, conv_b2 + (size_t)l * HD,
                           hA, stats);
        hipLaunchKernelGGL(k_bn, gBn, blk, 0, stream, hA, stats,
                           bn_g + (size_t)l * HD, bn_b + (size_t)l * HD);
    }

    // final layer + post mlp
    hipMemsetAsync(hB, 0, hbytes, stream);
    hipLaunchKernelGGL(k_scatter, gScat, blk, 0, stream, src, dst, hA, hB);
    hipLaunchKernelGGL(k_final, gConv, blk, 0, stream, hA, hB,
                       conv_w1 + (size_t)2 * HD * HD, conv_b1 + (size_t)2 * HD,
                       conv_w2 + (size_t)2 * HD * HD, conv_b2 + (size_t)2 * HD,
                       post_w1, post_b1, post_w2, post_b2, out);
}

// Round 2
// 972.769 us; speedup vs baseline: 1.4775x; 1.4775x over previous
//
#include <hip/hip_runtime.h>
#include <hip/hip_bf16.h>

#define NN 100000      // nodes
#define EE 1600000     // edges
#define HD 64
#define SLOPE 0.01f
#define BN_EPS 1e-5f
#define CHUNK 1024
#define NCHUNK 98      // ceil(NN / CHUNK)

__device__ __forceinline__ float bcast(float v, int i) {
    return __uint_as_float((unsigned)__builtin_amdgcn_readlane((int)__float_as_uint(v), i));
}
__device__ __forceinline__ float lrelu(float v) { return v > 0.f ? v : SLOPE * v; }

// ---------------- pre-linear: h = x @ W + b ----------------
__global__ __launch_bounds__(256) void k_pre(const float* __restrict__ x,
                                             const float* __restrict__ W,
                                             const float* __restrict__ b,
                                             float* __restrict__ h) {
    __shared__ float Ws[HD * HD];
    int tid = threadIdx.x;
    for (int k = tid; k < HD * HD / 4; k += 256)
        ((float4*)Ws)[k] = ((const float4*)W)[k];
    __syncthreads();
    int lane = tid & 63;
    int gw = (blockIdx.x * 256 + tid) >> 6;
    int nw = (gridDim.x * 256) >> 6;
    float bb = b[lane];
    for (int row0 = gw * 4; row0 < NN; row0 += nw * 4) {
        float z[4], y[4];
#pragma unroll
        for (int r = 0; r < 4; r++) {
            z[r] = x[(size_t)(row0 + r) * HD + lane];
            y[r] = bb;
        }
        for (int i = 0; i < HD; i++) {
            float w = Ws[i * HD + lane];
#pragma unroll
            for (int r = 0; r < 4; r++) y[r] = fmaf(bcast(z[r], i), w, y[r]);
        }
#pragma unroll
        for (int r = 0; r < 4; r++) h[(size_t)(row0 + r) * HD + lane] = y[r];
    }
}

// ---------------- CSR build ----------------
__global__ __launch_bounds__(256) void k_hist(const int* __restrict__ dst,
                                              int* __restrict__ counts) {
    int i = (blockIdx.x * 256 + threadIdx.x) * 4;
    if (i + 3 < EE) {
        int4 d = *(const int4*)(dst + i);
        atomicAdd(&counts[d.x], 1);
        atomicAdd(&counts[d.y], 1);
        atomicAdd(&counts[d.z], 1);
        atomicAdd(&counts[d.w], 1);
    } else {
        for (; i < EE; i++) atomicAdd(&counts[dst[i]], 1);
    }
}

// exclusive scan of counts[NN] -> row_ptr[NN+1]; decoupled redundant-sum scan
__global__ __launch_bounds__(256) void k_scan(const int* __restrict__ counts,
                                              int* __restrict__ row_ptr) {
    __shared__ int lsum[256];
    int b = blockIdx.x, tid = threadIdx.x;
    // phase A: global offset = sum of counts[0 .. b*CHUNK)
    int pres = 0;
    for (int i = tid; i < b * CHUNK; i += 256) pres += counts[i];
    lsum[tid] = pres;
    __syncthreads();
    for (int s = 128; s > 0; s >>= 1) {
        if (tid < s) lsum[tid] += lsum[tid + s];
        __syncthreads();
    }
    int offset = lsum[0];
    __syncthreads();
    // phase B: scan own chunk (4 elements per thread)
    int base = b * CHUNK + tid * 4;
    int c[4], tsum = 0;
#pragma unroll
    for (int k = 0; k < 4; k++) {
        int idx = base + k;
        c[k] = (idx < NN) ? counts[idx] : 0;
        tsum += c[k];
    }
    lsum[tid] = tsum;
    __syncthreads();
    for (int s = 1; s < 256; s <<= 1) {
        int t = (tid >= s) ? lsum[tid - s] : 0;
        __syncthreads();
        lsum[tid] += t;
        __syncthreads();
    }
    int run = offset + lsum[tid] - tsum;  // exclusive prefix for this thread
#pragma unroll
    for (int k = 0; k < 4; k++) {
        int idx = base + k;
        if (idx < NN) row_ptr[idx] = run;
        run += c[k];
    }
    if (b == 0 && tid == 0) row_ptr[NN] = EE;
}

__global__ __launch_bounds__(256) void k_fill(const int* __restrict__ src,
                                              const int* __restrict__ dst,
                                              int* __restrict__ cursor,
                                              int* __restrict__ csr) {
    int i = (blockIdx.x * 256 + threadIdx.x) * 4;
    if (i + 3 < EE) {
        int4 d = *(const int4*)(dst + i);
        int4 s = *(const int4*)(src + i);
        csr[atomicAdd(&cursor[d.x], 1)] = s.x;
        csr[atomicAdd(&cursor[d.y], 1)] = s.y;
        csr[atomicAdd(&cursor[d.z], 1)] = s.z;
        csr[atomicAdd(&cursor[d.w], 1)] = s.w;
    } else {
        for (; i < EE; i++) csr[atomicAdd(&cursor[dst[i]], 1)] = src[i];
    }
}

// ---------------- fused gather + GINConv (+input-BN, +output BN stats) ----------------
__global__ __launch_bounds__(256) void k_gin(const float* __restrict__ h,
                                             const int* __restrict__ row_ptr,
                                             const int* __restrict__ csr,
                                             const float* __restrict__ w1,
                                             const float* __restrict__ b1,
                                             const float* __restrict__ w2,
                                             const float* __restrict__ b2,
                                             const float* __restrict__ bn_stats,
                                             const float* __restrict__ bn_g,
                                             const float* __restrict__ bn_b,
                                             int apply_bn, int do_stats,
                                             float* __restrict__ out,
                                             float* __restrict__ stats_out) {
    __shared__ float w1s[HD * HD];
    __shared__ float w2s[HD * HD];
    int tid = threadIdx.x;
    for (int k = tid; k < HD * HD / 4; k += 256) {
        ((float4*)w1s)[k] = ((const float4*)w1)[k];
        ((float4*)w2s)[k] = ((const float4*)w2)[k];
    }
    __syncthreads();
    int lane = tid & 63;
    int gw = (blockIdx.x * 256 + tid) >> 6;
    int nw = (gridDim.x * 256) >> 6;
    float bb1 = b1[lane], bb2 = b2[lane];
    float sc = 1.f, sh = 0.f;
    if (apply_bn) {
        float inv = 1.f / (float)NN;
        float mu = bn_stats[lane] * inv;
        float var = bn_stats[64 + lane] * inv - mu * mu;
        sc = rsqrtf(var + BN_EPS) * bn_g[lane];
        sh = bn_b[lane] - mu * sc;
    }
    float s1 = 0.f, s2 = 0.f;
    for (int n0 = gw * 4; n0 < NN; n0 += nw * 4) {
        int r[5];
#pragma unroll
        for (int k = 0; k < 5; k++) r[k] = __builtin_amdgcn_readfirstlane(row_ptr[n0 + k]);
        float z[4];
#pragma unroll
        for (int kk = 0; kk < 4; kk++) {
            float a0 = 0.f, a1 = 0.f, a2 = 0.f, a3 = 0.f;
            int e = r[kk], re = r[kk + 1];
            for (; e + 4 <= re; e += 4) {
                int i0 = csr[e], i1 = csr[e + 1], i2 = csr[e + 2], i3 = csr[e + 3];
                a0 += h[(size_t)i0 * HD + lane];
                a1 += h[(size_t)i1 * HD + lane];
                a2 += h[(size_t)i2 * HD + lane];
                a3 += h[(size_t)i3 * HD + lane];
            }
            for (; e < re; e++) a0 += h[(size_t)csr[e] * HD + lane];
            float zz = h[(size_t)(n0 + kk) * HD + lane] + ((a0 + a1) + (a2 + a3));
            // BN folded into the input read: sum of affine-transformed rows
            z[kk] = apply_bn ? fmaf(zz, sc, (float)(re - r[kk] + 1) * sh) : zz;
        }
        float y[4] = {bb1, bb1, bb1, bb1};
        for (int i = 0; i < HD; i++) {
            float w = w1s[i * HD + lane];
#pragma unroll
            for (int kk = 0; kk < 4; kk++) y[kk] = fmaf(bcast(z[kk], i), w, y[kk]);
        }
#pragma unroll
        for (int kk = 0; kk < 4; kk++) { z[kk] = lrelu(y[kk]); y[kk] = bb2; }
        for (int i = 0; i < HD; i++) {
            float w = w2s[i * HD + lane];
#pragma unroll
            for (int kk = 0; kk < 4; kk++) y[kk] = fmaf(bcast(z[kk], i), w, y[kk]);
        }
#pragma unroll
        for (int kk = 0; kk < 4; kk++) {
            out[(size_t)(n0 + kk) * HD + lane] = y[kk];
            s1 += y[kk];
            s2 += y[kk] * y[kk];
        }
    }
    if (do_stats) {
        atomicAdd(&stats_out[lane], s1);
        atomicAdd(&stats_out[64 + lane], s2);
    }
}

// ---------------- post MLP: out = lrelu(h@w1+b1)@w2+b2 ----------------
__global__ __launch_bounds__(256) void k_post(const float* __restrict__ h,
                                              const float* __restrict__ w1,
                                              const float* __restrict__ b1,
                                              const float* __restrict__ w2,
                                              const float* __restrict__ b2,
                                              float* __restrict__ out) {
    __shared__ float w1s[HD * HD];
    __shared__ float w2s[HD * HD];
    int tid = threadIdx.x;
    for (int k = tid; k < HD * HD / 4; k += 256) {
        ((float4*)w1s)[k] = ((const float4*)w1)[k];
        ((float4*)w2s)[k] = ((const float4*)w2)[k];
    }
    __syncthreads();
    int lane = tid & 63;
    int gw = (blockIdx.x * 256 + tid) >> 6;
    int nw = (gridDim.x * 256) >> 6;
    float bb1 = b1[lane], bb2 = b2[lane];
    for (int row0 = gw * 4; row0 < NN; row0 += nw * 4) {
        float z[4], y[4];
#pragma unroll
        for (int r = 0; r < 4; r++) {
            z[r] = h[(size_t)(row0 + r) * HD + lane];
            y[r] = bb1;
        }
        for (int i = 0; i < HD; i++) {
            float w = w1s[i * HD + lane];
#pragma unroll
            for (int r = 0; r < 4; r++) y[r] = fmaf(bcast(z[r], i), w, y[r]);
        }
#pragma unroll
        for (int r = 0; r < 4; r++) { z[r] = lrelu(y[r]); y[r] = bb2; }
        for (int i = 0; i < HD; i++) {
            float w = w2s[i * HD + lane];
#pragma unroll
            for (int r = 0; r < 4; r++) y[r] = fmaf(bcast(z[r], i), w, y[r]);
        }
#pragma unroll
        for (int r = 0; r < 4; r++) out[(size_t)(row0 + r) * HD + lane] = y[r];
    }
}

extern "C" void kernel_launch(void* const* d_in, const int* in_sizes, int n_in,
                              void* d_out, int out_size, void* d_ws, size_t ws_size,
                              hipStream_t stream) {
    const float* x = (const float*)d_in[0];
    const int* edge = (const int*)d_in[1];
    const float* pre_w = (const float*)d_in[2];
    const float* pre_b = (const float*)d_in[3];
    const float* conv_w1 = (const float*)d_in[4];
    const float* conv_b1 = (const float*)d_in[5];
    const float* conv_w2 = (const float*)d_in[6];
    const float* conv_b2 = (const float*)d_in[7];
    const float* bn_g = (const float*)d_in[8];
    const float* bn_b = (const float*)d_in[9];
    const float* post_w1 = (const float*)d_in[10];
    const float* post_b1 = (const float*)d_in[11];
    const float* post_w2 = (const float*)d_in[12];
    const float* post_b2 = (const float*)d_in[13];
    float* out = (float*)d_out;

    const int* src = edge;       // edge_index[0]
    const int* dst = edge + EE;  // edge_index[1]

    float* hA = (float*)d_ws;                 // NN*HD f32
    float* hB = hA + (size_t)NN * HD;         // NN*HD f32
    float* stats0 = hB + (size_t)NN * HD;     // 128 f32
    float* stats1 = stats0 + 128;             // 128 f32
    int* counts = (int*)(stats1 + 128);       // NN ints (reused as cursor)
    int* row_ptr = counts + NN;               // NN+1 ints (pad to NN+4)
    int* csr = row_ptr + NN + 4;              // EE ints

    dim3 blk(256);

    // CSR build
    hipMemsetAsync(counts, 0, NN * sizeof(int), stream);
    hipMemsetAsync(stats0, 0, 256 * sizeof(float), stream);
    hipLaunchKernelGGL(k_hist, dim3(1563), blk, 0, stream, dst, counts);
    hipLaunchKernelGGL(k_scan, dim3(NCHUNK), blk, 0, stream, counts, row_ptr);
    hipMemcpyAsync(counts, row_ptr, NN * sizeof(int), hipMemcpyDeviceToDevice, stream);
    hipLaunchKernelGGL(k_fill, dim3(1563), blk, 0, stream, src, dst, counts, csr);

    // pre-linear
    hipLaunchKernelGGL(k_pre, dim3(1024), blk, 0, stream, x, pre_w, pre_b, hA);

    // layer 0: gin (no input BN), accumulate stats0
    hipLaunchKernelGGL(k_gin, dim3(1280), blk, 0, stream, hA, row_ptr, csr,
                       conv_w1, conv_b1, conv_w2, conv_b2,
                       (const float*)nullptr, (const float*)nullptr, (const float*)nullptr,
                       0, 1, hB, stats0);
    // layer 1: gin with BN(l0) folded on input, accumulate stats1
    hipLaunchKernelGGL(k_gin, dim3(1280), blk, 0, stream, hB, row_ptr, csr,
                       conv_w1 + (size_t)1 * HD * HD, conv_b1 + 1 * HD,
                       conv_w2 + (size_t)1 * HD * HD, conv_b2 + 1 * HD,
                       stats0, bn_g, bn_b, 1, 1, hA, stats1);
    // layer 2: gin with BN(l1) folded on input, no stats
    hipLaunchKernelGGL(k_gin, dim3(1280), blk, 0, stream, hA, row_ptr, csr,
                       conv_w1 + (size_t)2 * HD * HD, conv_b1 + 2 * HD,
                       conv_w2 + (size_t)2 * HD * HD, conv_b2 + 2 * HD,
                       stats1, bn_g + HD, bn_b + HD, 1, 0, hB, stats1);
    // post MLP
    hipLaunchKernelGGL(k_post, dim3(1024), blk, 0, stream, hB,
                       post_w1, post_b1, post_w2, post_b2, out);
}

// Round 3
// 823.711 us; speedup vs baseline: 1.7449x; 1.1810x over previous
//
#include <hip/hip_runtime.h>
#include <hip/hip_bf16.h>

#define NN 100000      // nodes
#define EE 1600000     // edges
#define HD 64
#define SLOPE 0.01f
#define BN_EPS 1e-5f
#define CHUNK 1024
#define NCHUNK 98      // ceil(NN / CHUNK)

__device__ __forceinline__ float bcast(float v, int i) {
    return __uint_as_float((unsigned)__builtin_amdgcn_readlane((int)__float_as_uint(v), i));
}
__device__ __forceinline__ float lrelu(float v) { return v > 0.f ? v : SLOPE * v; }

// ---------------- pre-linear: h = x @ W + b ----------------
__global__ __launch_bounds__(256) void k_pre(const float* __restrict__ x,
                                             const float* __restrict__ W,
                                             const float* __restrict__ b,
                                             float* __restrict__ h) {
    __shared__ float Ws[HD * HD];
    int tid = threadIdx.x;
    for (int k = tid; k < HD * HD / 4; k += 256)
        ((float4*)Ws)[k] = ((const float4*)W)[k];
    __syncthreads();
    int lane = tid & 63;
    int gw = (blockIdx.x * 256 + tid) >> 6;
    int nw = (gridDim.x * 256) >> 6;
    float bb = b[lane];
    for (int row0 = gw * 4; row0 < NN; row0 += nw * 4) {
        float z[4], y[4];
#pragma unroll
        for (int r = 0; r < 4; r++) {
            z[r] = x[(size_t)(row0 + r) * HD + lane];
            y[r] = bb;
        }
        for (int i = 0; i < HD; i++) {
            float w = Ws[i * HD + lane];
#pragma unroll
            for (int r = 0; r < 4; r++) y[r] = fmaf(bcast(z[r], i), w, y[r]);
        }
#pragma unroll
        for (int r = 0; r < 4; r++) h[(size_t)(row0 + r) * HD + lane] = y[r];
    }
}

// ---------------- CSR build ----------------
__global__ __launch_bounds__(256) void k_hist(const int* __restrict__ dst,
                                              int* __restrict__ counts) {
    int i = (blockIdx.x * 256 + threadIdx.x) * 4;
    if (i + 3 < EE) {
        int4 d = *(const int4*)(dst + i);
        atomicAdd(&counts[d.x], 1);
        atomicAdd(&counts[d.y], 1);
        atomicAdd(&counts[d.z], 1);
        atomicAdd(&counts[d.w], 1);
    } else {
        for (; i < EE; i++) atomicAdd(&counts[dst[i]], 1);
    }
}

__global__ __launch_bounds__(256) void k_scan(const int* __restrict__ counts,
                                              int* __restrict__ row_ptr) {
    __shared__ int lsum[256];
    int b = blockIdx.x, tid = threadIdx.x;
    int pres = 0;
    for (int i = tid; i < b * CHUNK; i += 256) pres += counts[i];
    lsum[tid] = pres;
    __syncthreads();
    for (int s = 128; s > 0; s >>= 1) {
        if (tid < s) lsum[tid] += lsum[tid + s];
        __syncthreads();
    }
    int offset = lsum[0];
    __syncthreads();
    int base = b * CHUNK + tid * 4;
    int c[4], tsum = 0;
#pragma unroll
    for (int k = 0; k < 4; k++) {
        int idx = base + k;
        c[k] = (idx < NN) ? counts[idx] : 0;
        tsum += c[k];
    }
    lsum[tid] = tsum;
    __syncthreads();
    for (int s = 1; s < 256; s <<= 1) {
        int t = (tid >= s) ? lsum[tid - s] : 0;
        __syncthreads();
        lsum[tid] += t;
        __syncthreads();
    }
    int run = offset + lsum[tid] - tsum;
#pragma unroll
    for (int k = 0; k < 4; k++) {
        int idx = base + k;
        if (idx < NN) row_ptr[idx] = run;
        run += c[k];
    }
    if (b == 0 && tid == 0) row_ptr[NN] = EE;
}

__global__ __launch_bounds__(256) void k_fill(const int* __restrict__ src,
                                              const int* __restrict__ dst,
                                              int* __restrict__ cursor,
                                              int* __restrict__ csr) {
    int i = (blockIdx.x * 256 + threadIdx.x) * 4;
    if (i + 3 < EE) {
        int4 d = *(const int4*)(dst + i);
        int4 s = *(const int4*)(src + i);
        csr[atomicAdd(&cursor[d.x], 1)] = s.x;
        csr[atomicAdd(&cursor[d.y], 1)] = s.y;
        csr[atomicAdd(&cursor[d.z], 1)] = s.z;
        csr[atomicAdd(&cursor[d.w], 1)] = s.w;
    } else {
        for (; i < EE; i++) csr[atomicAdd(&cursor[dst[i]], 1)] = src[i];
    }
}

// ---------------- gather: z[n] = (h[n] + sum_nbr h) [*BN folded] ----------------
// 16-lane group per node (float4/lane), 4 nodes per wave, high occupancy.
__global__ __launch_bounds__(256, 8) void k_gather(const float* __restrict__ h,
                                                   const int* __restrict__ row_ptr,
                                                   const int* __restrict__ csr,
                                                   const float* __restrict__ bn_stats,
                                                   const float* __restrict__ bn_g,
                                                   const float* __restrict__ bn_b,
                                                   int apply_bn,
                                                   float* __restrict__ z) {
    int tid = threadIdx.x;
    int lane = tid & 63;
    int g = lane >> 4;              // node sub-group 0..3
    int fq = lane & 15;             // float4 index within row (feature/4)
    int wave = (blockIdx.x * 256 + tid) >> 6;
    int node = wave * 4 + g;
    if (node >= NN) return;

    float4 sc = make_float4(1.f, 1.f, 1.f, 1.f);
    float4 sh = make_float4(0.f, 0.f, 0.f, 0.f);
    if (apply_bn) {
        float inv = 1.f / (float)NN;
        float* scp = (float*)&sc;
        float* shp = (float*)&sh;
#pragma unroll
        for (int j = 0; j < 4; j++) {
            int f = fq * 4 + j;
            float mu = bn_stats[f] * inv;
            float var = bn_stats[64 + f] * inv - mu * mu;
            float s = rsqrtf(var + BN_EPS) * bn_g[f];
            scp[j] = s;
            shp[j] = bn_b[f] - mu * s;
        }
    }

    const float4* hv = (const float4*)h;  // row = 16 float4
    int r0 = row_ptr[node], re = row_ptr[node + 1];
    float4 a0 = hv[(size_t)node * 16 + fq];  // self
    float4 a1 = make_float4(0.f, 0.f, 0.f, 0.f);
    float4 a2 = a1, a3 = a1;
    int e = r0;
    for (; e + 4 <= re; e += 4) {
        int i0 = csr[e], i1 = csr[e + 1], i2 = csr[e + 2], i3 = csr[e + 3];
        float4 v0 = hv[(size_t)i0 * 16 + fq];
        float4 v1 = hv[(size_t)i1 * 16 + fq];
        float4 v2 = hv[(size_t)i2 * 16 + fq];
        float4 v3 = hv[(size_t)i3 * 16 + fq];
        a0 += v0; a1 += v1; a2 += v2; a3 += v3;
    }
    for (; e < re; e++) a0 += hv[(size_t)csr[e] * 16 + fq];
    float4 s4 = (a0 + a1) + (a2 + a3);
    if (apply_bn) {
        float cnt = (float)(re - r0 + 1);
        s4.x = fmaf(s4.x, sc.x, cnt * sh.x);
        s4.y = fmaf(s4.y, sc.y, cnt * sh.y);
        s4.z = fmaf(s4.z, sc.z, cnt * sh.z);
        s4.w = fmaf(s4.w, sc.w, cnt * sh.w);
    }
    ((float4*)z)[(size_t)node * 16 + fq] = s4;
}

// ---------------- MLP: out = lrelu(z@w1+b1)@w2+b2, optional BN stats ----------------
__global__ __launch_bounds__(256) void k_mlp(const float* __restrict__ z_in,
                                             const float* __restrict__ w1,
                                             const float* __restrict__ b1,
                                             const float* __restrict__ w2,
                                             const float* __restrict__ b2,
                                             int do_stats,
                                             float* __restrict__ out,
                                             float* __restrict__ stats_out) {
    __shared__ float w1s[HD * HD];
    __shared__ float w2s[HD * HD];
    __shared__ float red[2][256];
    int tid = threadIdx.x;
    for (int k = tid; k < HD * HD / 4; k += 256) {
        ((float4*)w1s)[k] = ((const float4*)w1)[k];
        ((float4*)w2s)[k] = ((const float4*)w2)[k];
    }
    __syncthreads();
    int lane = tid & 63;
    int gw = (blockIdx.x * 256 + tid) >> 6;
    int nw = (gridDim.x * 256) >> 6;
    float bb1 = b1[lane], bb2 = b2[lane];
    float s1 = 0.f, s2 = 0.f;
    for (int n0 = gw * 4; n0 < NN; n0 += nw * 4) {
        float z[4], y[4];
#pragma unroll
        for (int r = 0; r < 4; r++) {
            z[r] = z_in[(size_t)(n0 + r) * HD + lane];
            y[r] = bb1;
        }
        for (int i = 0; i < HD; i++) {
            float w = w1s[i * HD + lane];
#pragma unroll
            for (int r = 0; r < 4; r++) y[r] = fmaf(bcast(z[r], i), w, y[r]);
        }
#pragma unroll
        for (int r = 0; r < 4; r++) { z[r] = lrelu(y[r]); y[r] = bb2; }
        for (int i = 0; i < HD; i++) {
            float w = w2s[i * HD + lane];
#pragma unroll
            for (int r = 0; r < 4; r++) y[r] = fmaf(bcast(z[r], i), w, y[r]);
        }
#pragma unroll
        for (int r = 0; r < 4; r++) {
            out[(size_t)(n0 + r) * HD + lane] = y[r];
            s1 += y[r];
            s2 += y[r] * y[r];
        }
    }
    if (do_stats) {
        red[0][tid] = s1;
        red[1][tid] = s2;
        __syncthreads();
        if (tid < 64) {
            float t1 = red[0][tid] + red[0][tid + 64] + red[0][tid + 128] + red[0][tid + 192];
            float t2 = red[1][tid] + red[1][tid + 64] + red[1][tid + 128] + red[1][tid + 192];
            atomicAdd(&stats_out[tid], t1);
            atomicAdd(&stats_out[64 + tid], t2);
        }
    }
}

// ---------------- final: out = POST(MLP2(z)) ----------------
__global__ __launch_bounds__(256) void k_final(const float* __restrict__ z_in,
                                               const float* __restrict__ w1,
                                               const float* __restrict__ b1,
                                               const float* __restrict__ w2,
                                               const float* __restrict__ b2,
                                               const float* __restrict__ pw1,
                                               const float* __restrict__ pb1,
                                               const float* __restrict__ pw2,
                                               const float* __restrict__ pb2,
                                               float* __restrict__ out) {
    __shared__ float w1s[HD * HD];
    __shared__ float w2s[HD * HD];
    __shared__ float pw1s[HD * HD];
    __shared__ float pw2s[HD * HD];
    int tid = threadIdx.x;
    for (int k = tid; k < HD * HD / 4; k += 256) {
        ((float4*)w1s)[k] = ((const float4*)w1)[k];
        ((float4*)w2s)[k] = ((const float4*)w2)[k];
        ((float4*)pw1s)[k] = ((const float4*)pw1)[k];
        ((float4*)pw2s)[k] = ((const float4*)pw2)[k];
    }
    __syncthreads();
    int lane = tid & 63;
    int gw = (blockIdx.x * 256 + tid) >> 6;
    int nw = (gridDim.x * 256) >> 6;
    float bb1 = b1[lane], bb2 = b2[lane], pbb1 = pb1[lane], pbb2 = pb2[lane];
    for (int n0 = gw * 4; n0 < NN; n0 += nw * 4) {
        float z[4], y[4];
#pragma unroll
        for (int r = 0; r < 4; r++) {
            z[r] = z_in[(size_t)(n0 + r) * HD + lane];
            y[r] = bb1;
        }
        for (int i = 0; i < HD; i++) {
            float w = w1s[i * HD + lane];
#pragma unroll
            for (int r = 0; r < 4; r++) y[r] = fmaf(bcast(z[r], i), w, y[r]);
        }
#pragma unroll
        for (int r = 0; r < 4; r++) { z[r] = lrelu(y[r]); y[r] = bb2; }
        for (int i = 0; i < HD; i++) {
            float w = w2s[i * HD + lane];
#pragma unroll
            for (int r = 0; r < 4; r++) y[r] = fmaf(bcast(z[r], i), w, y[r]);
        }
#pragma unroll
        for (int r = 0; r < 4; r++) { z[r] = y[r]; y[r] = pbb1; }
        for (int i = 0; i < HD; i++) {
            float w = pw1s[i * HD + lane];
#pragma unroll
            for (int r = 0; r < 4; r++) y[r] = fmaf(bcast(z[r], i), w, y[r]);
        }
#pragma unroll
        for (int r = 0; r < 4; r++) { z[r] = lrelu(y[r]); y[r] = pbb2; }
        for (int i = 0; i < HD; i++) {
            float w = pw2s[i * HD + lane];
#pragma unroll
            for (int r = 0; r < 4; r++) y[r] = fmaf(bcast(z[r], i), w, y[r]);
        }
#pragma unroll
        for (int r = 0; r < 4; r++) out[(size_t)(n0 + r) * HD + lane] = y[r];
    }
}

extern "C" void kernel_launch(void* const* d_in, const int* in_sizes, int n_in,
                              void* d_out, int out_size, void* d_ws, size_t ws_size,
                              hipStream_t stream) {
    const float* x = (const float*)d_in[0];
    const int* edge = (const int*)d_in[1];
    const float* pre_w = (const float*)d_in[2];
    const float* pre_b = (const float*)d_in[3];
    const float* conv_w1 = (const float*)d_in[4];
    const float* conv_b1 = (const float*)d_in[5];
    const float* conv_w2 = (const float*)d_in[6];
    const float* conv_b2 = (const float*)d_in[7];
    const float* bn_g = (const float*)d_in[8];
    const float* bn_b = (const float*)d_in[9];
    const float* post_w1 = (const float*)d_in[10];
    const float* post_b1 = (const float*)d_in[11];
    const float* post_w2 = (const float*)d_in[12];
    const float* post_b2 = (const float*)d_in[13];
    float* out = (float*)d_out;

    const int* src = edge;       // edge_index[0]
    const int* dst = edge + EE;  // edge_index[1]

    float* hA = (float*)d_ws;                 // NN*HD f32
    float* hB = hA + (size_t)NN * HD;         // NN*HD f32
    float* stats0 = hB + (size_t)NN * HD;     // 128 f32
    float* stats1 = stats0 + 128;             // 128 f32
    int* counts = (int*)(stats1 + 128);       // NN ints (reused as cursor)
    int* row_ptr = counts + NN;               // NN+1 ints (padded)
    int* csr = row_ptr + NN + 4;              // EE ints

    dim3 blk(256);
    dim3 gGather(6250);   // 25000 waves = ceil(NN/4)
    dim3 gMlp(1280);

    // CSR build
    hipMemsetAsync(counts, 0, NN * sizeof(int), stream);
    hipMemsetAsync(stats0, 0, 256 * sizeof(float), stream);
    hipLaunchKernelGGL(k_hist, dim3(1563), blk, 0, stream, dst, counts);
    hipLaunchKernelGGL(k_scan, dim3(NCHUNK), blk, 0, stream, counts, row_ptr);
    hipMemcpyAsync(counts, row_ptr, NN * sizeof(int), hipMemcpyDeviceToDevice, stream);
    hipLaunchKernelGGL(k_fill, dim3(1563), blk, 0, stream, src, dst, counts, csr);

    // pre-linear
    hipLaunchKernelGGL(k_pre, dim3(1024), blk, 0, stream, x, pre_w, pre_b, hA);

    // layer 0
    hipLaunchKernelGGL(k_gather, gGather, blk, 0, stream, hA, row_ptr, csr,
                       (const float*)nullptr, (const float*)nullptr, (const float*)nullptr, 0, hB);
    hipLaunchKernelGGL(k_mlp, gMlp, blk, 0, stream, hB,
                       conv_w1, conv_b1, conv_w2, conv_b2, 1, hA, stats0);
    // layer 1 (BN(l0) folded into gather)
    hipLaunchKernelGGL(k_gather, gGather, blk, 0, stream, hA, row_ptr, csr,
                       stats0, bn_g, bn_b, 1, hB);
    hipLaunchKernelGGL(k_mlp, gMlp, blk, 0, stream, hB,
                       conv_w1 + (size_t)1 * HD * HD, conv_b1 + 1 * HD,
                       conv_w2 + (size_t)1 * HD * HD, conv_b2 + 1 * HD, 1, hA, stats1);
    // layer 2 (BN(l1) folded into gather) + fused final
    hipLaunchKernelGGL(k_gather, gGather, blk, 0, stream, hA, row_ptr, csr,
                       stats1, bn_g + HD, bn_b + HD, 1, hB);
    hipLaunchKernelGGL(k_final, gMlp, blk, 0, stream, hB,
                       conv_w1 + (size_t)2 * HD * HD, conv_b1 + 2 * HD,
                       conv_w2 + (size_t)2 * HD * HD, conv_b2 + 2 * HD,
                       post_w1, post_b1, post_w2, post_b2, out);
}

// Round 4
// 769.102 us; speedup vs baseline: 1.8688x; 1.0710x over previous
//
#include <hip/hip_runtime.h>
#include <hip/hip_bf16.h>

#define NN 100000      // nodes
#define EE 1600000     // edges
#define HD 64
#define SLOPE 0.01f
#define BN_EPS 1e-5f
#define CHUNK 1024
#define NCHUNK 98      // ceil(NN / CHUNK)
#define ROWS 8         // rows per wave in GEMV kernels

__device__ __forceinline__ float bcast(float v, int i) {
    return __uint_as_float((unsigned)__builtin_amdgcn_readlane((int)__float_as_uint(v), i));
}
__device__ __forceinline__ float lrelu(float v) { return v > 0.f ? v : SLOPE * v; }

// y[r] = b + sum_i z[r][i] * W[i][lane]  -- weights straight from global (L1-cached,
// coalesced 256B/instr); no LDS so occupancy is VGPR-limited only.
__device__ __forceinline__ void gemv8(const float* __restrict__ W, float bb,
                                      const float (&z)[ROWS], float (&y)[ROWS], int lane) {
#pragma unroll
    for (int r = 0; r < ROWS; r++) y[r] = bb;
#pragma unroll 8
    for (int i = 0; i < HD; i++) {
        float w = W[i * HD + lane];
#pragma unroll
        for (int r = 0; r < ROWS; r++) y[r] = fmaf(bcast(z[r], i), w, y[r]);
    }
}

// ---------------- pre-linear: h = x @ W + b ----------------
__global__ __launch_bounds__(256, 4) void k_pre(const float* __restrict__ x,
                                                const float* __restrict__ W,
                                                const float* __restrict__ b,
                                                float* __restrict__ h) {
    int tid = threadIdx.x;
    int lane = tid & 63;
    int wave = (blockIdx.x * 256 + tid) >> 6;   // 0..12499
    int n0 = wave * ROWS;
    if (n0 >= NN) return;
    float bb = b[lane];
    float z[ROWS], y[ROWS];
#pragma unroll
    for (int r = 0; r < ROWS; r++) z[r] = x[(size_t)(n0 + r) * HD + lane];
    gemv8(W, bb, z, y, lane);
#pragma unroll
    for (int r = 0; r < ROWS; r++) h[(size_t)(n0 + r) * HD + lane] = y[r];
}

// ---------------- CSR build ----------------
__global__ __launch_bounds__(256) void k_hist(const int* __restrict__ dst,
                                              int* __restrict__ counts) {
    int i = (blockIdx.x * 256 + threadIdx.x) * 4;
    if (i + 3 < EE) {
        int4 d = *(const int4*)(dst + i);
        atomicAdd(&counts[d.x], 1);
        atomicAdd(&counts[d.y], 1);
        atomicAdd(&counts[d.z], 1);
        atomicAdd(&counts[d.w], 1);
    } else {
        for (; i < EE; i++) atomicAdd(&counts[dst[i]], 1);
    }
}

__global__ __launch_bounds__(256) void k_scan(const int* __restrict__ counts,
                                              int* __restrict__ row_ptr) {
    __shared__ int lsum[256];
    int b = blockIdx.x, tid = threadIdx.x;
    int pres = 0;
    for (int i = tid; i < b * CHUNK; i += 256) pres += counts[i];
    lsum[tid] = pres;
    __syncthreads();
    for (int s = 128; s > 0; s >>= 1) {
        if (tid < s) lsum[tid] += lsum[tid + s];
        __syncthreads();
    }
    int offset = lsum[0];
    __syncthreads();
    int base = b * CHUNK + tid * 4;
    int c[4], tsum = 0;
#pragma unroll
    for (int k = 0; k < 4; k++) {
        int idx = base + k;
        c[k] = (idx < NN) ? counts[idx] : 0;
        tsum += c[k];
    }
    lsum[tid] = tsum;
    __syncthreads();
    for (int s = 1; s < 256; s <<= 1) {
        int t = (tid >= s) ? lsum[tid - s] : 0;
        __syncthreads();
        lsum[tid] += t;
        __syncthreads();
    }
    int run = offset + lsum[tid] - tsum;
#pragma unroll
    for (int k = 0; k < 4; k++) {
        int idx = base + k;
        if (idx < NN) row_ptr[idx] = run;
        run += c[k];
    }
    if (b == 0 && tid == 0) row_ptr[NN] = EE;
}

__global__ __launch_bounds__(256) void k_fill(const int* __restrict__ src,
                                              const int* __restrict__ dst,
                                              int* __restrict__ cursor,
                                              int* __restrict__ csr) {
    int i = (blockIdx.x * 256 + threadIdx.x) * 4;
    if (i + 3 < EE) {
        int4 d = *(const int4*)(dst + i);
        int4 s = *(const int4*)(src + i);
        csr[atomicAdd(&cursor[d.x], 1)] = s.x;
        csr[atomicAdd(&cursor[d.y], 1)] = s.y;
        csr[atomicAdd(&cursor[d.z], 1)] = s.z;
        csr[atomicAdd(&cursor[d.w], 1)] = s.w;
    } else {
        for (; i < EE; i++) csr[atomicAdd(&cursor[dst[i]], 1)] = src[i];
    }
}

// ---------------- gather: z[n] = (h[n] + sum_nbr h) [*BN folded] ----------------
__global__ __launch_bounds__(256, 8) void k_gather(const float* __restrict__ h,
                                                   const int* __restrict__ row_ptr,
                                                   const int* __restrict__ csr,
                                                   const float* __restrict__ bn_stats,
                                                   const float* __restrict__ bn_g,
                                                   const float* __restrict__ bn_b,
                                                   int apply_bn,
                                                   float* __restrict__ z) {
    int tid = threadIdx.x;
    int lane = tid & 63;
    int g = lane >> 4;              // node sub-group 0..3
    int fq = lane & 15;             // float4 index within row
    int wave = (blockIdx.x * 256 + tid) >> 6;
    int node = wave * 4 + g;
    if (node >= NN) return;

    float4 sc = make_float4(1.f, 1.f, 1.f, 1.f);
    float4 sh = make_float4(0.f, 0.f, 0.f, 0.f);
    if (apply_bn) {
        float inv = 1.f / (float)NN;
        float* scp = (float*)&sc;
        float* shp = (float*)&sh;
#pragma unroll
        for (int j = 0; j < 4; j++) {
            int f = fq * 4 + j;
            float mu = bn_stats[f] * inv;
            float var = bn_stats[64 + f] * inv - mu * mu;
            float s = rsqrtf(var + BN_EPS) * bn_g[f];
            scp[j] = s;
            shp[j] = bn_b[f] - mu * s;
        }
    }

    const float4* hv = (const float4*)h;  // row = 16 float4
    int r0 = row_ptr[node], re = row_ptr[node + 1];
    float4 a0 = hv[(size_t)node * 16 + fq];  // self
    float4 a1 = make_float4(0.f, 0.f, 0.f, 0.f);
    float4 a2 = a1, a3 = a1;
    int e = r0;
    for (; e + 4 <= re; e += 4) {
        int i0 = csr[e], i1 = csr[e + 1], i2 = csr[e + 2], i3 = csr[e + 3];
        float4 v0 = hv[(size_t)i0 * 16 + fq];
        float4 v1 = hv[(size_t)i1 * 16 + fq];
        float4 v2 = hv[(size_t)i2 * 16 + fq];
        float4 v3 = hv[(size_t)i3 * 16 + fq];
        a0 += v0; a1 += v1; a2 += v2; a3 += v3;
    }
    for (; e < re; e++) a0 += hv[(size_t)csr[e] * 16 + fq];
    float4 s4 = (a0 + a1) + (a2 + a3);
    if (apply_bn) {
        float cnt = (float)(re - r0 + 1);
        s4.x = fmaf(s4.x, sc.x, cnt * sh.x);
        s4.y = fmaf(s4.y, sc.y, cnt * sh.y);
        s4.z = fmaf(s4.z, sc.z, cnt * sh.z);
        s4.w = fmaf(s4.w, sc.w, cnt * sh.w);
    }
    ((float4*)z)[(size_t)node * 16 + fq] = s4;
}

// ---------------- MLP: out = lrelu(z@w1+b1)@w2+b2, optional BN stats ----------------
__global__ __launch_bounds__(256, 4) void k_mlp(const float* __restrict__ z_in,
                                                const float* __restrict__ w1,
                                                const float* __restrict__ b1,
                                                const float* __restrict__ w2,
                                                const float* __restrict__ b2,
                                                int do_stats,
                                                float* __restrict__ out,
                                                float* __restrict__ stats_out) {
    __shared__ float red[2][256];
    int tid = threadIdx.x;
    int lane = tid & 63;
    int wave = (blockIdx.x * 256 + tid) >> 6;
    int n0 = wave * ROWS;
    if (n0 >= NN) return;
    float bb1 = b1[lane], bb2 = b2[lane];
    float z[ROWS], y[ROWS];
#pragma unroll
    for (int r = 0; r < ROWS; r++) z[r] = z_in[(size_t)(n0 + r) * HD + lane];
    gemv8(w1, bb1, z, y, lane);
#pragma unroll
    for (int r = 0; r < ROWS; r++) z[r] = lrelu(y[r]);
    gemv8(w2, bb2, z, y, lane);
    float s1 = 0.f, s2 = 0.f;
#pragma unroll
    for (int r = 0; r < ROWS; r++) {
        out[(size_t)(n0 + r) * HD + lane] = y[r];
        s1 += y[r];
        s2 += y[r] * y[r];
    }
    if (do_stats) {
        red[0][tid] = s1;
        red[1][tid] = s2;
        __syncthreads();
        if (tid < 64) {
            float t1 = red[0][tid] + red[0][tid + 64] + red[0][tid + 128] + red[0][tid + 192];
            float t2 = red[1][tid] + red[1][tid + 64] + red[1][tid + 128] + red[1][tid + 192];
            atomicAdd(&stats_out[tid], t1);
            atomicAdd(&stats_out[64 + tid], t2);
        }
    }
}

// ---------------- final: out = POST(MLP2(z)) ----------------
__global__ __launch_bounds__(256, 4) void k_final(const float* __restrict__ z_in,
                                                  const float* __restrict__ w1,
                                                  const float* __restrict__ b1,
                                                  const float* __restrict__ w2,
                                                  const float* __restrict__ b2,
                                                  const float* __restrict__ pw1,
                                                  const float* __restrict__ pb1,
                                                  const float* __restrict__ pw2,
                                                  const float* __restrict__ pb2,
                                                  float* __restrict__ out) {
    int tid = threadIdx.x;
    int lane = tid & 63;
    int wave = (blockIdx.x * 256 + tid) >> 6;
    int n0 = wave * ROWS;
    if (n0 >= NN) return;
    float z[ROWS], y[ROWS];
#pragma unroll
    for (int r = 0; r < ROWS; r++) z[r] = z_in[(size_t)(n0 + r) * HD + lane];
    gemv8(w1, b1[lane], z, y, lane);
#pragma unroll
    for (int r = 0; r < ROWS; r++) z[r] = lrelu(y[r]);
    gemv8(w2, b2[lane], z, y, lane);
#pragma unroll
    for (int r = 0; r < ROWS; r++) z[r] = y[r];
    gemv8(pw1, pb1[lane], z, y, lane);
#pragma unroll
    for (int r = 0; r < ROWS; r++) z[r] = lrelu(y[r]);
    gemv8(pw2, pb2[lane], z, y, lane);
#pragma unroll
    for (int r = 0; r < ROWS; r++) out[(size_t)(n0 + r) * HD + lane] = y[r];
}

extern "C" void kernel_launch(void* const* d_in, const int* in_sizes, int n_in,
                              void* d_out, int out_size, void* d_ws, size_t ws_size,
                              hipStream_t stream) {
    const float* x = (const float*)d_in[0];
    const int* edge = (const int*)d_in[1];
    const float* pre_w = (const float*)d_in[2];
    const float* pre_b = (const float*)d_in[3];
    const float* conv_w1 = (const float*)d_in[4];
    const float* conv_b1 = (const float*)d_in[5];
    const float* conv_w2 = (const float*)d_in[6];
    const float* conv_b2 = (const float*)d_in[7];
    const float* bn_g = (const float*)d_in[8];
    const float* bn_b = (const float*)d_in[9];
    const float* post_w1 = (const float*)d_in[10];
    const float* post_b1 = (const float*)d_in[11];
    const float* post_w2 = (const float*)d_in[12];
    const float* post_b2 = (const float*)d_in[13];
    float* out = (float*)d_out;

    const int* src = edge;       // edge_index[0]
    const int* dst = edge + EE;  // edge_index[1]

    float* hA = (float*)d_ws;                 // NN*HD f32
    float* hB = hA + (size_t)NN * HD;         // NN*HD f32
    float* stats0 = hB + (size_t)NN * HD;     // 128 f32
    float* stats1 = stats0 + 128;             // 128 f32
    int* counts = (int*)(stats1 + 128);       // NN ints (reused as cursor)
    int* row_ptr = counts + NN;               // NN+1 ints (padded)
    int* csr = row_ptr + NN + 4;              // EE ints

    dim3 blk(256);
    dim3 gGather(6250);   // ceil(NN/4) waves
    dim3 gMlp(3125);      // 12500 waves x 8 rows = 100000

    // CSR build
    hipMemsetAsync(counts, 0, NN * sizeof(int), stream);
    hipMemsetAsync(stats0, 0, 256 * sizeof(float), stream);
    hipLaunchKernelGGL(k_hist, dim3(1563), blk, 0, stream, dst, counts);
    hipLaunchKernelGGL(k_scan, dim3(NCHUNK), blk, 0, stream, counts, row_ptr);
    hipMemcpyAsync(counts, row_ptr, NN * sizeof(int), hipMemcpyDeviceToDevice, stream);
    hipLaunchKernelGGL(k_fill, dim3(1563), blk, 0, stream, src, dst, counts, csr);

    // pre-linear
    hipLaunchKernelGGL(k_pre, gMlp, blk, 0, stream, x, pre_w, pre_b, hA);

    // layer 0
    hipLaunchKernelGGL(k_gather, gGather, blk, 0, stream, hA, row_ptr, csr,
                       (const float*)nullptr, (const float*)nullptr, (const float*)nullptr, 0, hB);
    hipLaunchKernelGGL(k_mlp, gMlp, blk, 0, stream, hB,
                       conv_w1, conv_b1, conv_w2, conv_b2, 1, hA, stats0);
    // layer 1 (BN(l0) folded into gather)
    hipLaunchKernelGGL(k_gather, gGather, blk, 0, stream, hA, row_ptr, csr,
                       stats0, bn_g, bn_b, 1, hB);
    hipLaunchKernelGGL(k_mlp, gMlp, blk, 0, stream, hB,
                       conv_w1 + (size_t)1 * HD * HD, conv_b1 + 1 * HD,
                       conv_w2 + (size_t)1 * HD * HD, conv_b2 + 1 * HD, 1, hA, stats1);
    // layer 2 (BN(l1) folded into gather) + fused final
    hipLaunchKernelGGL(k_gather, gGather, blk, 0, stream, hA, row_ptr, csr,
                       stats1, bn_g + HD, bn_b + HD, 1, hB);
    hipLaunchKernelGGL(k_final, gMlp, blk, 0, stream, hB,
                       conv_w1 + (size_t)2 * HD * HD, conv_b1 + 2 * HD,
                       conv_w2 + (size_t)2 * HD * HD, conv_b2 + 2 * HD,
                       post_w1, post_b1, post_w2, post_b2, out);
}